// Round 2
// baseline (117.171 us; speedup 1.0000x reference)
//
#include <hip/hip_runtime.h>
#include <math.h>

#define BATCH 512
#define DIN   5120
#define DST   16
#define RK    160
#define NJ    192   // 160 dt_rank + 16 B + 16 C

// ---------------------------------------------------------------------------
// Kernel 1: P[j,b] = sum_d W[j,d] * x[b,d]   (j<160: W_dt_rank, 160..175: W_B,
// 176..191: W_C).  Split-K with f32 atomicAdd into workspace.
// grid: (3 j-tiles of 64, 8 b-tiles of 64, 16 k-slices of 320), block 256.
// ---------------------------------------------------------------------------
__global__ __launch_bounds__(256) void k_proj(
    const float* __restrict__ x, const float* __restrict__ Wdtr,
    const float* __restrict__ WB, const float* __restrict__ WC,
    float* __restrict__ o_dtr, float* __restrict__ o_B, float* __restrict__ o_C)
{
  const int t  = threadIdx.x;
  const int j0 = blockIdx.x * 64;
  const int b0 = blockIdx.y * 64;
  const int k_start = blockIdx.z * 320;

  __shared__ float sW[16][68];   // [k][j], padded
  __shared__ float sX[16][68];   // [k][b]

  const int tj = t & 15, tb = t >> 4;       // compute mapping: 4 j x 4 b
  const int srow = t >> 2, sq = t & 3;      // staging mapping: row, k-quad

  const int j = j0 + srow;
  const float* wrow;
  if (j < RK)            wrow = Wdtr + (size_t)j * DIN;
  else if (j < RK + DST) wrow = WB   + (size_t)(j - RK) * DIN;
  else                   wrow = WC   + (size_t)(j - RK - DST) * DIN;
  const float* xrow = x + (size_t)(b0 + srow) * DIN;

  float acc[4][4] = {};

  for (int kc = 0; kc < 20; ++kc) {
    const int k = k_start + kc * 16 + sq * 4;
    const float4 wv = *(const float4*)(wrow + k);
    const float4 xv = *(const float4*)(xrow + k);
    __syncthreads();
    sW[sq*4+0][srow] = wv.x; sW[sq*4+1][srow] = wv.y;
    sW[sq*4+2][srow] = wv.z; sW[sq*4+3][srow] = wv.w;
    sX[sq*4+0][srow] = xv.x; sX[sq*4+1][srow] = xv.y;
    sX[sq*4+2][srow] = xv.z; sX[sq*4+3][srow] = xv.w;
    __syncthreads();
#pragma unroll
    for (int kk = 0; kk < 16; ++kk) {
      const float4 wf = *(const float4*)&sW[kk][tj*4];
      const float4 xf = *(const float4*)&sX[kk][tb*4];
      const float w[4] = {wf.x, wf.y, wf.z, wf.w};
      const float xr[4] = {xf.x, xf.y, xf.z, xf.w};
#pragma unroll
      for (int a = 0; a < 4; ++a)
#pragma unroll
        for (int c = 0; c < 4; ++c)
          acc[a][c] = fmaf(w[a], xr[c], acc[a][c]);
    }
  }

#pragma unroll
  for (int a = 0; a < 4; ++a) {
    const int jj = j0 + tj * 4 + a;
#pragma unroll
    for (int c = 0; c < 4; ++c) {
      const int bb = b0 + tb * 4 + c;
      const float v = acc[a][c];
      if (jj < RK)            atomicAdd(&o_dtr[(size_t)bb * RK + jj], v);
      else if (jj < RK + DST) atomicAdd(&o_B[(size_t)bb * DST + (jj - RK)], v);
      else                    atomicAdd(&o_C[(size_t)bb * DST + (jj - RK - DST)], v);
    }
  }
}

// ---------------------------------------------------------------------------
// Kernel 2: dt[b,d] = softplus(dtr[b,:] @ Wdt[d,:] + bdt[d])  (GEMM, K=160)
// grid: (80 d-tiles of 64, 8 b-tiles of 64), block 256, 4x4 register tile.
// ---------------------------------------------------------------------------
__global__ __launch_bounds__(256) void k_dt(
    const float* __restrict__ dtr, const float* __restrict__ Wdt,
    const float* __restrict__ bdt, float* __restrict__ dt)
{
  const int t  = threadIdx.x;
  const int d0 = blockIdx.x * 64;
  const int b0 = blockIdx.y * 64;

  __shared__ float sWT[32][68];   // [r][d]
  __shared__ float sDT[32][68];   // [r][b]

  const int tdl = t & 15, tbl = t >> 4;
  const int srow = t >> 2, sq = t & 3;

  const float* wrow = Wdt + (size_t)(d0 + srow) * RK;
  const float* drow = dtr + (size_t)(b0 + srow) * RK;

  float acc[4][4] = {};   // [id][ib]

  for (int rc = 0; rc < 5; ++rc) {
    const float4 w0 = *(const float4*)(wrow + rc*32 + sq*4);
    const float4 w1 = *(const float4*)(wrow + rc*32 + 16 + sq*4);
    const float4 a0 = *(const float4*)(drow + rc*32 + sq*4);
    const float4 a1 = *(const float4*)(drow + rc*32 + 16 + sq*4);
    __syncthreads();
    sWT[sq*4+0][srow] = w0.x; sWT[sq*4+1][srow] = w0.y;
    sWT[sq*4+2][srow] = w0.z; sWT[sq*4+3][srow] = w0.w;
    sWT[sq*4+16][srow] = w1.x; sWT[sq*4+17][srow] = w1.y;
    sWT[sq*4+18][srow] = w1.z; sWT[sq*4+19][srow] = w1.w;
    sDT[sq*4+0][srow] = a0.x; sDT[sq*4+1][srow] = a0.y;
    sDT[sq*4+2][srow] = a0.z; sDT[sq*4+3][srow] = a0.w;
    sDT[sq*4+16][srow] = a1.x; sDT[sq*4+17][srow] = a1.y;
    sDT[sq*4+18][srow] = a1.z; sDT[sq*4+19][srow] = a1.w;
    __syncthreads();
#pragma unroll
    for (int kk = 0; kk < 32; ++kk) {
      const float4 wf = *(const float4*)&sWT[kk][tdl*4];
      const float4 df = *(const float4*)&sDT[kk][tbl*4];
      const float w[4] = {wf.x, wf.y, wf.z, wf.w};
      const float dd[4] = {df.x, df.y, df.z, df.w};
#pragma unroll
      for (int a = 0; a < 4; ++a)
#pragma unroll
        for (int c = 0; c < 4; ++c)
          acc[a][c] = fmaf(w[a], dd[c], acc[a][c]);
    }
  }

#pragma unroll
  for (int ib = 0; ib < 4; ++ib) {
    const int b = b0 + tbl * 4 + ib;
#pragma unroll
    for (int id = 0; id < 4; ++id) {
      const int d = d0 + tdl * 4 + id;
      const float pre = acc[id][ib] + bdt[d];
      const float dtv = (pre > 20.f) ? pre : log1pf(__expf(pre));
      dt[(size_t)b * DIN + d] = dtv;
    }
  }
}

// ---------------------------------------------------------------------------
// Kernel 3: pure streaming state update + y. One thread per (b,d).
//   y[b,d] = sum_s (exp(A[d,s]*dt)*h[b,d,s] + dt*Bc[b,s]*x[b,d]) * Cc[b,s]
//            + D[d]*x[b,d]
// grid-exact: 512*5120/256 = 10240 blocks.
// ---------------------------------------------------------------------------
__global__ __launch_bounds__(256) void k_y(
    const float* __restrict__ dt, const float* __restrict__ Bc,
    const float* __restrict__ Cc, const float* __restrict__ A,
    const float* __restrict__ Dp, const float* __restrict__ x,
    const float* __restrict__ h,  float* __restrict__ y)
{
  const int idx = blockIdx.x * 256 + threadIdx.x;   // < BATCH*DIN exactly
  const int b = idx / DIN;
  const int d = idx - b * DIN;

  const float dtv = dt[idx];
  const float xv  = x[idx];
  float yv = Dp[d] * xv;

  const float* hp = h  + (size_t)idx * DST;
  const float* Ap = A  + (size_t)d * DST;
  const float* Bp = Bc + (size_t)b * DST;
  const float* Cp = Cc + (size_t)b * DST;

  const float dtx = dtv * xv;

#pragma unroll
  for (int s4 = 0; s4 < 4; ++s4) {
    const float4 h4 = *(const float4*)(hp + s4 * 4);
    const float4 A4 = *(const float4*)(Ap + s4 * 4);
    const float4 B4 = *(const float4*)(Bp + s4 * 4);
    const float4 C4 = *(const float4*)(Cp + s4 * 4);
    const float hv[4] = {h4.x, h4.y, h4.z, h4.w};
    const float Av[4] = {A4.x, A4.y, A4.z, A4.w};
    const float Bv[4] = {B4.x, B4.y, B4.z, B4.w};
    const float Cv[4] = {C4.x, C4.y, C4.z, C4.w};
#pragma unroll
    for (int s = 0; s < 4; ++s) {
      const float dA = __expf(Av[s] * dtv);
      const float hn = fmaf(dA, hv[s], dtx * Bv[s]);
      yv = fmaf(hn, Cv[s], yv);
    }
  }
  y[idx] = yv;
}

extern "C" void kernel_launch(void* const* d_in, const int* in_sizes, int n_in,
                              void* d_out, int out_size, void* d_ws, size_t ws_size,
                              hipStream_t stream) {
  const float* x    = (const float*)d_in[0];
  const float* Wdtr = (const float*)d_in[1];
  const float* Wdt  = (const float*)d_in[2];
  const float* bdt  = (const float*)d_in[3];
  const float* WB   = (const float*)d_in[4];
  const float* WC   = (const float*)d_in[5];
  const float* A    = (const float*)d_in[6];
  const float* Dp   = (const float*)d_in[7];
  const float* h    = (const float*)d_in[8];
  float* y = (float*)d_out;

  float* ws_dtr = (float*)d_ws;                   // [512][160]
  float* ws_B   = ws_dtr + (size_t)BATCH * RK;    // [512][16]
  float* ws_C   = ws_B   + (size_t)BATCH * DST;   // [512][16]
  float* ws_dt  = ws_C   + (size_t)BATCH * DST;   // [512][5120]

  hipMemsetAsync(d_ws, 0, (size_t)BATCH * NJ * sizeof(float), stream);

  k_proj<<<dim3(3, 8, 16), 256, 0, stream>>>(x, Wdtr, WB, WC, ws_dtr, ws_B, ws_C);
  k_dt<<<dim3(80, 8), 256, 0, stream>>>(ws_dtr, Wdt, bdt, ws_dt);
  k_y<<<dim3((BATCH * DIN) / 256), 256, 0, stream>>>(ws_dt, ws_B, ws_C, A, Dp, x, h, y);
}

// Round 3
// 102.508 us; speedup vs baseline: 1.1430x; 1.1430x over previous
//
#include <hip/hip_runtime.h>
#include <math.h>

#define BATCH 512
#define DIN   5120
#define DST   16
#define RK    160
#define NJ    192   // 160 dt_rank + 16 B + 16 C
#define NZ    16    // split-K slices

// ---------------------------------------------------------------------------
// Kernel 1: P[j,b] = sum_d W[j,d] * x[b,d]   (j<160: W_dt_rank, 160..175: W_B,
// 176..191: W_C).  Split-K WITHOUT atomics: each block writes its 64x64 tile
// partial (per-thread 16 floats, contiguous) to ws_part. No zero-init needed.
// grid: (3 j-tiles, 8 b-tiles, 16 k-slices), block 256.
// ---------------------------------------------------------------------------
__global__ __launch_bounds__(256) void k_proj(
    const float* __restrict__ x, const float* __restrict__ Wdtr,
    const float* __restrict__ WB, const float* __restrict__ WC,
    float* __restrict__ part)
{
  const int t  = threadIdx.x;
  const int j0 = blockIdx.x * 64;
  const int b0 = blockIdx.y * 64;
  const int k_start = blockIdx.z * 320;

  __shared__ float sW[16][68];   // [k][j], padded
  __shared__ float sX[16][68];   // [k][b]

  const int tj = t & 15, tb = t >> 4;       // compute mapping: 4 j x 4 b
  const int srow = t >> 2, sq = t & 3;      // staging mapping: row, k-quad

  const int j = j0 + srow;
  const float* wrow;
  if (j < RK)            wrow = Wdtr + (size_t)j * DIN;
  else if (j < RK + DST) wrow = WB   + (size_t)(j - RK) * DIN;
  else                   wrow = WC   + (size_t)(j - RK - DST) * DIN;
  const float* xrow = x + (size_t)(b0 + srow) * DIN;

  float acc[4][4] = {};

  for (int kc = 0; kc < 20; ++kc) {
    const int k = k_start + kc * 16 + sq * 4;
    const float4 wv = *(const float4*)(wrow + k);
    const float4 xv = *(const float4*)(xrow + k);
    __syncthreads();
    sW[sq*4+0][srow] = wv.x; sW[sq*4+1][srow] = wv.y;
    sW[sq*4+2][srow] = wv.z; sW[sq*4+3][srow] = wv.w;
    sX[sq*4+0][srow] = xv.x; sX[sq*4+1][srow] = xv.y;
    sX[sq*4+2][srow] = xv.z; sX[sq*4+3][srow] = xv.w;
    __syncthreads();
#pragma unroll
    for (int kk = 0; kk < 16; ++kk) {
      const float4 wf = *(const float4*)&sW[kk][tj*4];
      const float4 xf = *(const float4*)&sX[kk][tb*4];
      const float w[4] = {wf.x, wf.y, wf.z, wf.w};
      const float xr[4] = {xf.x, xf.y, xf.z, xf.w};
#pragma unroll
      for (int a = 0; a < 4; ++a)
#pragma unroll
        for (int c = 0; c < 4; ++c)
          acc[a][c] = fmaf(w[a], xr[c], acc[a][c]);
    }
  }

  // coalesced partial store: block base + t*16, 4x float4 per thread
  float* pb = part + ((((size_t)blockIdx.z * 3 + blockIdx.x) * 8 + blockIdx.y) << 12) + t * 16;
#pragma unroll
  for (int a = 0; a < 4; ++a)
    *(float4*)(pb + a * 4) = make_float4(acc[a][0], acc[a][1], acc[a][2], acc[a][3]);
}

// ---------------------------------------------------------------------------
// Kernel 1b: sum the 16 k-slice partials and scatter into dtr/B/C layouts.
// grid: 3*8*4096/256 = 384 blocks.
// ---------------------------------------------------------------------------
__global__ __launch_bounds__(256) void k_reduce(
    const float* __restrict__ part,
    float* __restrict__ o_dtr, float* __restrict__ o_B, float* __restrict__ o_C)
{
  const int g = blockIdx.x * 256 + threadIdx.x;   // < 98304
  const int f  = g & 4095;
  const int bx = (g >> 12) & 7;
  const int jx = g >> 15;

  float s = 0.f;
#pragma unroll
  for (int z = 0; z < NZ; ++z)
    s += part[(((size_t)(z * 3 + jx) * 8 + bx) << 12) + f];

  const int t = f >> 4, a = (f >> 2) & 3, c = f & 3;
  const int jj = jx * 64 + (t & 15) * 4 + a;
  const int bb = bx * 64 + (t >> 4) * 4 + c;
  if (jj < RK)            o_dtr[(size_t)bb * RK + jj] = s;
  else if (jj < RK + DST) o_B[(size_t)bb * DST + (jj - RK)] = s;
  else                    o_C[(size_t)bb * DST + (jj - RK - DST)] = s;
}

// ---------------------------------------------------------------------------
// Kernel 2: dt[b,d] = softplus(dtr[b,:] @ Wdt[d,:] + bdt[d])  (GEMM, K=160)
// grid: (80 d-tiles of 64, 8 b-tiles of 64), block 256, 4x4 register tile.
// ---------------------------------------------------------------------------
__global__ __launch_bounds__(256) void k_dt(
    const float* __restrict__ dtr, const float* __restrict__ Wdt,
    const float* __restrict__ bdt, float* __restrict__ dt)
{
  const int t  = threadIdx.x;
  const int d0 = blockIdx.x * 64;
  const int b0 = blockIdx.y * 64;

  __shared__ float sWT[32][68];   // [r][d]
  __shared__ float sDT[32][68];   // [r][b]

  const int tdl = t & 15, tbl = t >> 4;
  const int srow = t >> 2, sq = t & 3;

  const float* wrow = Wdt + (size_t)(d0 + srow) * RK;
  const float* drow = dtr + (size_t)(b0 + srow) * RK;

  float acc[4][4] = {};   // [id][ib]

  for (int rc = 0; rc < 5; ++rc) {
    const float4 w0 = *(const float4*)(wrow + rc*32 + sq*4);
    const float4 w1 = *(const float4*)(wrow + rc*32 + 16 + sq*4);
    const float4 a0 = *(const float4*)(drow + rc*32 + sq*4);
    const float4 a1 = *(const float4*)(drow + rc*32 + 16 + sq*4);
    __syncthreads();
    sWT[sq*4+0][srow] = w0.x; sWT[sq*4+1][srow] = w0.y;
    sWT[sq*4+2][srow] = w0.z; sWT[sq*4+3][srow] = w0.w;
    sWT[sq*4+16][srow] = w1.x; sWT[sq*4+17][srow] = w1.y;
    sWT[sq*4+18][srow] = w1.z; sWT[sq*4+19][srow] = w1.w;
    sDT[sq*4+0][srow] = a0.x; sDT[sq*4+1][srow] = a0.y;
    sDT[sq*4+2][srow] = a0.z; sDT[sq*4+3][srow] = a0.w;
    sDT[sq*4+16][srow] = a1.x; sDT[sq*4+17][srow] = a1.y;
    sDT[sq*4+18][srow] = a1.z; sDT[sq*4+19][srow] = a1.w;
    __syncthreads();
#pragma unroll
    for (int kk = 0; kk < 32; ++kk) {
      const float4 wf = *(const float4*)&sWT[kk][tdl*4];
      const float4 df = *(const float4*)&sDT[kk][tbl*4];
      const float w[4] = {wf.x, wf.y, wf.z, wf.w};
      const float dd[4] = {df.x, df.y, df.z, df.w};
#pragma unroll
      for (int a = 0; a < 4; ++a)
#pragma unroll
        for (int c = 0; c < 4; ++c)
          acc[a][c] = fmaf(w[a], dd[c], acc[a][c]);
    }
  }

#pragma unroll
  for (int ib = 0; ib < 4; ++ib) {
    const int b = b0 + tbl * 4 + ib;
#pragma unroll
    for (int id = 0; id < 4; ++id) {
      const int d = d0 + tdl * 4 + id;
      const float pre = acc[id][ib] + bdt[d];
      const float dtv = (pre > 20.f) ? pre : log1pf(__expf(pre));
      dt[(size_t)b * DIN + d] = dtv;
    }
  }
}

// ---------------------------------------------------------------------------
// Kernel 3: pure streaming state update + y. One thread per (b,d).
// grid-exact: 512*5120/256 = 10240 blocks.
// ---------------------------------------------------------------------------
__global__ __launch_bounds__(256) void k_y(
    const float* __restrict__ dt, const float* __restrict__ Bc,
    const float* __restrict__ Cc, const float* __restrict__ A,
    const float* __restrict__ Dp, const float* __restrict__ x,
    const float* __restrict__ h,  float* __restrict__ y)
{
  const int idx = blockIdx.x * 256 + threadIdx.x;   // < BATCH*DIN exactly
  const int b = idx / DIN;
  const int d = idx - b * DIN;

  const float dtv = dt[idx];
  const float xv  = x[idx];
  float yv = Dp[d] * xv;

  const float* hp = h  + (size_t)idx * DST;
  const float* Ap = A  + (size_t)d * DST;
  const float* Bp = Bc + (size_t)b * DST;
  const float* Cp = Cc + (size_t)b * DST;

  const float dtx = dtv * xv;

#pragma unroll
  for (int s4 = 0; s4 < 4; ++s4) {
    const float4 h4 = *(const float4*)(hp + s4 * 4);
    const float4 A4 = *(const float4*)(Ap + s4 * 4);
    const float4 B4 = *(const float4*)(Bp + s4 * 4);
    const float4 C4 = *(const float4*)(Cp + s4 * 4);
    const float hv[4] = {h4.x, h4.y, h4.z, h4.w};
    const float Av[4] = {A4.x, A4.y, A4.z, A4.w};
    const float Bv[4] = {B4.x, B4.y, B4.z, B4.w};
    const float Cv[4] = {C4.x, C4.y, C4.z, C4.w};
#pragma unroll
    for (int s = 0; s < 4; ++s) {
      const float dA = __expf(Av[s] * dtv);
      const float hn = fmaf(dA, hv[s], dtx * Bv[s]);
      yv = fmaf(hn, Cv[s], yv);
    }
  }
  y[idx] = yv;
}

extern "C" void kernel_launch(void* const* d_in, const int* in_sizes, int n_in,
                              void* d_out, int out_size, void* d_ws, size_t ws_size,
                              hipStream_t stream) {
  const float* x    = (const float*)d_in[0];
  const float* Wdtr = (const float*)d_in[1];
  const float* Wdt  = (const float*)d_in[2];
  const float* bdt  = (const float*)d_in[3];
  const float* WB   = (const float*)d_in[4];
  const float* WC   = (const float*)d_in[5];
  const float* A    = (const float*)d_in[6];
  const float* Dp   = (const float*)d_in[7];
  const float* h    = (const float*)d_in[8];
  float* y = (float*)d_out;

  float* ws_part = (float*)d_ws;                        // 16*3*8*4096 = 1.57M floats
  float* ws_dtr  = ws_part + (size_t)NZ * 3 * 8 * 4096; // [512][160]
  float* ws_B    = ws_dtr + (size_t)BATCH * RK;         // [512][16]
  float* ws_C    = ws_B   + (size_t)BATCH * DST;        // [512][16]
  float* ws_dt   = ws_C   + (size_t)BATCH * DST;        // [512][5120]

  k_proj<<<dim3(3, 8, NZ), 256, 0, stream>>>(x, Wdtr, WB, WC, ws_part);
  k_reduce<<<dim3(384), 256, 0, stream>>>(ws_part, ws_dtr, ws_B, ws_C);
  k_dt<<<dim3(80, 8), 256, 0, stream>>>(ws_dtr, Wdt, bdt, ws_dt);
  k_y<<<dim3((BATCH * DIN) / 256), 256, 0, stream>>>(ws_dt, ws_B, ws_C, A, Dp, x, h, y);
}

// Round 4
// 101.477 us; speedup vs baseline: 1.1547x; 1.0102x over previous
//
#include <hip/hip_runtime.h>
#include <math.h>

#define BATCH 512
#define DIN   5120
#define DST   16
#define RK    160
#define NJ    192
#define NZ    32    // split-K slices (d-slice of 160 each)

// ---------------------------------------------------------------------------
// Kernel 1: P[j,b] = sum_d W[j,d] * x[b,d]  (j<160: W_dt_rank, then B, C).
// Split-K, atomics-free: block writes 64x64 tile partial to ws_part.
// grid (3 j, 8 b, 32 z), block 256, 10 k-iters of 16, global->LDS prefetch.
// ---------------------------------------------------------------------------
__global__ __launch_bounds__(256) void k_proj(
    const float* __restrict__ x, const float* __restrict__ Wdtr,
    const float* __restrict__ WB, const float* __restrict__ WC,
    float* __restrict__ part)
{
  const int t  = threadIdx.x;
  const int j0 = blockIdx.x * 64;
  const int b0 = blockIdx.y * 64;
  const int k_start = blockIdx.z * 160;

  __shared__ float sW[16][68];   // [k][j]
  __shared__ float sX[16][68];   // [k][b]

  const int tj = t & 15, tb = t >> 4;   // compute: 4 j x 4 b
  const int srow = t >> 2, sq = t & 3;  // staging: row, k-quad

  const int j = j0 + srow;
  const float* wrow;
  if (j < RK)            wrow = Wdtr + (size_t)j * DIN;
  else if (j < RK + DST) wrow = WB   + (size_t)(j - RK) * DIN;
  else                   wrow = WC   + (size_t)(j - RK - DST) * DIN;
  const float* xrow = x + (size_t)(b0 + srow) * DIN;

  float acc[4][4] = {};

  // prefetch iter 0
  float4 wv = *(const float4*)(wrow + k_start + sq * 4);
  float4 xv = *(const float4*)(xrow + k_start + sq * 4);

  for (int kc = 0; kc < 10; ++kc) {
    __syncthreads();   // previous iteration's readers done
    sW[sq*4+0][srow] = wv.x; sW[sq*4+1][srow] = wv.y;
    sW[sq*4+2][srow] = wv.z; sW[sq*4+3][srow] = wv.w;
    sX[sq*4+0][srow] = xv.x; sX[sq*4+1][srow] = xv.y;
    sX[sq*4+2][srow] = xv.z; sX[sq*4+3][srow] = xv.w;
    __syncthreads();
    if (kc < 9) {   // issue next-tile loads; latency hides under compute
      const int k = k_start + (kc + 1) * 16 + sq * 4;
      wv = *(const float4*)(wrow + k);
      xv = *(const float4*)(xrow + k);
    }
#pragma unroll
    for (int kk = 0; kk < 16; ++kk) {
      const float4 wf = *(const float4*)&sW[kk][tj*4];
      const float4 xf = *(const float4*)&sX[kk][tb*4];
      const float w[4] = {wf.x, wf.y, wf.z, wf.w};
      const float xr[4] = {xf.x, xf.y, xf.z, xf.w};
#pragma unroll
      for (int a = 0; a < 4; ++a)
#pragma unroll
        for (int c = 0; c < 4; ++c)
          acc[a][c] = fmaf(w[a], xr[c], acc[a][c]);
    }
  }

  float* pb = part + ((((size_t)blockIdx.z * 3 + blockIdx.x) * 8 + blockIdx.y) << 12) + t * 16;
#pragma unroll
  for (int a = 0; a < 4; ++a)
    *(float4*)(pb + a * 4) = make_float4(acc[a][0], acc[a][1], acc[a][2], acc[a][3]);
}

// ---------------------------------------------------------------------------
// Kernel 1b: sum 32 k-slice partials, scatter into dtr/B/C. 384 blocks.
// ---------------------------------------------------------------------------
__global__ __launch_bounds__(256) void k_reduce(
    const float* __restrict__ part,
    float* __restrict__ o_dtr, float* __restrict__ o_B, float* __restrict__ o_C)
{
  const int g = blockIdx.x * 256 + threadIdx.x;   // < 98304
  const int f  = g & 4095;
  const int bx = (g >> 12) & 7;
  const int jx = g >> 15;

  float s = 0.f;
#pragma unroll
  for (int z = 0; z < NZ; ++z)
    s += part[(((size_t)(z * 3 + jx) * 8 + bx) << 12) + f];

  const int t = f >> 4, a = (f >> 2) & 3, c = f & 3;
  const int jj = jx * 64 + (t & 15) * 4 + a;
  const int bb = bx * 64 + (t >> 4) * 4 + c;
  if (jj < RK)            o_dtr[(size_t)bb * RK + jj] = s;
  else if (jj < RK + DST) o_B[(size_t)bb * DST + (jj - RK)] = s;
  else                    o_C[(size_t)bb * DST + (jj - RK - DST)] = s;
}

// ---------------------------------------------------------------------------
// Kernel 2: dt[b,d] = softplus(dtr[b,:]@Wdt[d,:] + bdt[d]). 64d x 32b tiles,
// grid (80,16)=1280 blocks, thread tile 4d x 2b, K staged 5x32 w/ prefetch.
// ---------------------------------------------------------------------------
__global__ __launch_bounds__(256) void k_dt(
    const float* __restrict__ dtr, const float* __restrict__ Wdt,
    const float* __restrict__ bdt, float* __restrict__ dt)
{
  const int t  = threadIdx.x;
  const int d0 = blockIdx.x * 64;
  const int b0 = blockIdx.y * 32;

  __shared__ float sWT[32][68];   // [k][d]
  __shared__ float sDT[32][36];   // [k][b]

  const int tdl = t & 15, tbl = t >> 4;
  const int wrow_d = t >> 2, wq = t & 3;   // W staging: 64 rows, 2 quads each
  const int drow_b = t >> 3, dq = t & 7;   // dtr staging: 32 rows, 1 quad

  const float* wp = Wdt + (size_t)(d0 + wrow_d) * RK;
  const float* dp = dtr + (size_t)(b0 + drow_b) * RK;

  float acc[4][2] = {};

  float4 w0 = *(const float4*)(wp + wq * 4);
  float4 w1 = *(const float4*)(wp + 16 + wq * 4);
  float4 dd = *(const float4*)(dp + dq * 4);

  for (int rc = 0; rc < 5; ++rc) {
    __syncthreads();
    sWT[wq*4+0][wrow_d] = w0.x; sWT[wq*4+1][wrow_d] = w0.y;
    sWT[wq*4+2][wrow_d] = w0.z; sWT[wq*4+3][wrow_d] = w0.w;
    sWT[wq*4+16][wrow_d] = w1.x; sWT[wq*4+17][wrow_d] = w1.y;
    sWT[wq*4+18][wrow_d] = w1.z; sWT[wq*4+19][wrow_d] = w1.w;
    sDT[dq*4+0][drow_b] = dd.x; sDT[dq*4+1][drow_b] = dd.y;
    sDT[dq*4+2][drow_b] = dd.z; sDT[dq*4+3][drow_b] = dd.w;
    __syncthreads();
    if (rc < 4) {
      const int k = (rc + 1) * 32;
      w0 = *(const float4*)(wp + k + wq * 4);
      w1 = *(const float4*)(wp + k + 16 + wq * 4);
      dd = *(const float4*)(dp + k + dq * 4);
    }
#pragma unroll
    for (int kk = 0; kk < 32; ++kk) {
      const float4 wf = *(const float4*)&sWT[kk][tdl*4];
      const float2 df = *(const float2*)&sDT[kk][tbl*2];
      const float w[4] = {wf.x, wf.y, wf.z, wf.w};
#pragma unroll
      for (int a = 0; a < 4; ++a) {
        acc[a][0] = fmaf(w[a], df.x, acc[a][0]);
        acc[a][1] = fmaf(w[a], df.y, acc[a][1]);
      }
    }
  }

  const float4 b4 = *(const float4*)&bdt[d0 + tdl * 4];
  const float bv[4] = {b4.x, b4.y, b4.z, b4.w};
#pragma unroll
  for (int ib = 0; ib < 2; ++ib) {
    const int b = b0 + tbl * 2 + ib;
    float o[4];
#pragma unroll
    for (int a = 0; a < 4; ++a) {
      const float pre = acc[a][ib] + bv[a];
      o[a] = (pre > 20.f) ? pre : log1pf(__expf(pre));
    }
    *(float4*)&dt[(size_t)b * DIN + d0 + tdl * 4] = make_float4(o[0], o[1], o[2], o[3]);
  }
}

// ---------------------------------------------------------------------------
// Kernel 3: streaming state update + y. One thread per (b,d). 10240 blocks.
// ---------------------------------------------------------------------------
__global__ __launch_bounds__(256) void k_y(
    const float* __restrict__ dt, const float* __restrict__ Bc,
    const float* __restrict__ Cc, const float* __restrict__ A,
    const float* __restrict__ Dp, const float* __restrict__ x,
    const float* __restrict__ h,  float* __restrict__ y)
{
  const int idx = blockIdx.x * 256 + threadIdx.x;
  const int b = idx / DIN;
  const int d = idx - b * DIN;

  const float dtv = dt[idx];
  const float xv  = x[idx];
  float yv = Dp[d] * xv;

  const float* hp = h  + (size_t)idx * DST;
  const float* Ap = A  + (size_t)d * DST;
  const float* Bp = Bc + (size_t)b * DST;
  const float* Cp = Cc + (size_t)b * DST;

  const float dtx = dtv * xv;

#pragma unroll
  for (int s4 = 0; s4 < 4; ++s4) {
    const float4 h4 = *(const float4*)(hp + s4 * 4);
    const float4 A4 = *(const float4*)(Ap + s4 * 4);
    const float4 B4 = *(const float4*)(Bp + s4 * 4);
    const float4 C4 = *(const float4*)(Cp + s4 * 4);
    const float hv[4] = {h4.x, h4.y, h4.z, h4.w};
    const float Av[4] = {A4.x, A4.y, A4.z, A4.w};
    const float Bv[4] = {B4.x, B4.y, B4.z, B4.w};
    const float Cv[4] = {C4.x, C4.y, C4.z, C4.w};
#pragma unroll
    for (int s = 0; s < 4; ++s) {
      const float dA = __expf(Av[s] * dtv);
      const float hn = fmaf(dA, hv[s], dtx * Bv[s]);
      yv = fmaf(hn, Cv[s], yv);
    }
  }
  y[idx] = yv;
}

extern "C" void kernel_launch(void* const* d_in, const int* in_sizes, int n_in,
                              void* d_out, int out_size, void* d_ws, size_t ws_size,
                              hipStream_t stream) {
  const float* x    = (const float*)d_in[0];
  const float* Wdtr = (const float*)d_in[1];
  const float* Wdt  = (const float*)d_in[2];
  const float* bdt  = (const float*)d_in[3];
  const float* WB   = (const float*)d_in[4];
  const float* WC   = (const float*)d_in[5];
  const float* A    = (const float*)d_in[6];
  const float* Dp   = (const float*)d_in[7];
  const float* h    = (const float*)d_in[8];
  float* y = (float*)d_out;

  float* ws_part = (float*)d_ws;                        // 32*3*8*4096 floats
  float* ws_dtr  = ws_part + (size_t)NZ * 3 * 8 * 4096;
  float* ws_B    = ws_dtr + (size_t)BATCH * RK;
  float* ws_C    = ws_B   + (size_t)BATCH * DST;
  float* ws_dt   = ws_C   + (size_t)BATCH * DST;

  k_proj<<<dim3(3, 8, NZ), 256, 0, stream>>>(x, Wdtr, WB, WC, ws_part);
  k_reduce<<<dim3(384), 256, 0, stream>>>(ws_part, ws_dtr, ws_B, ws_C);
  k_dt<<<dim3(80, 16), 256, 0, stream>>>(ws_dtr, Wdt, bdt, ws_dt);
  k_y<<<dim3((BATCH * DIN) / 256), 256, 0, stream>>>(ws_dt, ws_B, ws_C, A, Dp, x, h, y);
}

// Round 5
// 93.155 us; speedup vs baseline: 1.2578x; 1.0893x over previous
//
#include <hip/hip_runtime.h>
#include <math.h>

#define BATCH 512
#define DIN   5120
#define DST   16
#define RK    160
#define NJ    192
#define NZ    32    // split-K slices

// ---------------------------------------------------------------------------
// Kernel 1: P[j,b] = sum_d W[j,d] * x[b,d]  (j<160: W_dt_rank, then B, C).
// Split-K, atomics-free: block writes 64x64 tile partial to ws_part.
// grid (3 j, 8 b, 32 z), block 256, 10 k-iters of 16, global->LDS prefetch.
// ---------------------------------------------------------------------------
__global__ __launch_bounds__(256) void k_proj(
    const float* __restrict__ x, const float* __restrict__ Wdtr,
    const float* __restrict__ WB, const float* __restrict__ WC,
    float* __restrict__ part)
{
  const int t  = threadIdx.x;
  const int j0 = blockIdx.x * 64;
  const int b0 = blockIdx.y * 64;
  const int k_start = blockIdx.z * 160;

  __shared__ float sW[16][68];   // [k][j]
  __shared__ float sX[16][68];   // [k][b]

  const int tj = t & 15, tb = t >> 4;   // compute: 4 j x 4 b
  const int srow = t >> 2, sq = t & 3;  // staging: row, k-quad

  const int j = j0 + srow;
  const float* wrow;
  if (j < RK)            wrow = Wdtr + (size_t)j * DIN;
  else if (j < RK + DST) wrow = WB   + (size_t)(j - RK) * DIN;
  else                   wrow = WC   + (size_t)(j - RK - DST) * DIN;
  const float* xrow = x + (size_t)(b0 + srow) * DIN;

  float acc[4][4] = {};

  float4 wv = *(const float4*)(wrow + k_start + sq * 4);
  float4 xv = *(const float4*)(xrow + k_start + sq * 4);

  for (int kc = 0; kc < 10; ++kc) {
    __syncthreads();
    sW[sq*4+0][srow] = wv.x; sW[sq*4+1][srow] = wv.y;
    sW[sq*4+2][srow] = wv.z; sW[sq*4+3][srow] = wv.w;
    sX[sq*4+0][srow] = xv.x; sX[sq*4+1][srow] = xv.y;
    sX[sq*4+2][srow] = xv.z; sX[sq*4+3][srow] = xv.w;
    __syncthreads();
    if (kc < 9) {
      const int k = k_start + (kc + 1) * 16 + sq * 4;
      wv = *(const float4*)(wrow + k);
      xv = *(const float4*)(xrow + k);
    }
#pragma unroll
    for (int kk = 0; kk < 16; ++kk) {
      const float4 wf = *(const float4*)&sW[kk][tj*4];
      const float4 xf = *(const float4*)&sX[kk][tb*4];
      const float w[4] = {wf.x, wf.y, wf.z, wf.w};
      const float xr[4] = {xf.x, xf.y, xf.z, xf.w};
#pragma unroll
      for (int a = 0; a < 4; ++a)
#pragma unroll
        for (int c = 0; c < 4; ++c)
          acc[a][c] = fmaf(w[a], xr[c], acc[a][c]);
    }
  }

  float* pb = part + ((((size_t)blockIdx.z * 3 + blockIdx.x) * 8 + blockIdx.y) << 12) + t * 16;
#pragma unroll
  for (int a = 0; a < 4; ++a)
    *(float4*)(pb + a * 4) = make_float4(acc[a][0], acc[a][1], acc[a][2], acc[a][3]);
}

// ---------------------------------------------------------------------------
// Kernel 1b: sum 32 k-slice partials, scatter into dtr/B/C. 384 blocks.
// ---------------------------------------------------------------------------
__global__ __launch_bounds__(256) void k_reduce(
    const float* __restrict__ part,
    float* __restrict__ o_dtr, float* __restrict__ o_B, float* __restrict__ o_C)
{
  const int g = blockIdx.x * 256 + threadIdx.x;   // < 98304
  const int f  = g & 4095;
  const int bx = (g >> 12) & 7;
  const int jx = g >> 15;

  float s = 0.f;
#pragma unroll
  for (int z = 0; z < NZ; ++z)
    s += part[(((size_t)(z * 3 + jx) * 8 + bx) << 12) + f];

  const int t = f >> 4, a = (f >> 2) & 3, c = f & 3;
  const int jj = jx * 64 + (t & 15) * 4 + a;
  const int bb = bx * 64 + (t >> 4) * 4 + c;
  if (jj < RK)            o_dtr[(size_t)bb * RK + jj] = s;
  else if (jj < RK + DST) o_B[(size_t)bb * DST + (jj - RK)] = s;
  else                    o_C[(size_t)bb * DST + (jj - RK - DST)] = s;
}

// ---------------------------------------------------------------------------
// Kernel 2: dt[b,d] = softplus(dtr[b,:]@Wdt[d,:] + bdt[d]). 64d x 32b tiles,
// grid (80,16)=1280 blocks, thread tile 4d x 2b, K staged 5x32 w/ prefetch.
// ---------------------------------------------------------------------------
__global__ __launch_bounds__(256) void k_dt(
    const float* __restrict__ dtr, const float* __restrict__ Wdt,
    const float* __restrict__ bdt, float* __restrict__ dt)
{
  const int t  = threadIdx.x;
  const int d0 = blockIdx.x * 64;
  const int b0 = blockIdx.y * 32;

  __shared__ float sWT[32][68];   // [k][d]
  __shared__ float sDT[32][36];   // [k][b]

  const int tdl = t & 15, tbl = t >> 4;
  const int wrow_d = t >> 2, wq = t & 3;
  const int drow_b = t >> 3, dq = t & 7;

  const float* wp = Wdt + (size_t)(d0 + wrow_d) * RK;
  const float* dp = dtr + (size_t)(b0 + drow_b) * RK;

  float acc[4][2] = {};

  float4 w0 = *(const float4*)(wp + wq * 4);
  float4 w1 = *(const float4*)(wp + 16 + wq * 4);
  float4 dd = *(const float4*)(dp + dq * 4);

  for (int rc = 0; rc < 5; ++rc) {
    __syncthreads();
    sWT[wq*4+0][wrow_d] = w0.x; sWT[wq*4+1][wrow_d] = w0.y;
    sWT[wq*4+2][wrow_d] = w0.z; sWT[wq*4+3][wrow_d] = w0.w;
    sWT[wq*4+16][wrow_d] = w1.x; sWT[wq*4+17][wrow_d] = w1.y;
    sWT[wq*4+18][wrow_d] = w1.z; sWT[wq*4+19][wrow_d] = w1.w;
    sDT[dq*4+0][drow_b] = dd.x; sDT[dq*4+1][drow_b] = dd.y;
    sDT[dq*4+2][drow_b] = dd.z; sDT[dq*4+3][drow_b] = dd.w;
    __syncthreads();
    if (rc < 4) {
      const int k = (rc + 1) * 32;
      w0 = *(const float4*)(wp + k + wq * 4);
      w1 = *(const float4*)(wp + k + 16 + wq * 4);
      dd = *(const float4*)(dp + k + dq * 4);
    }
#pragma unroll
    for (int kk = 0; kk < 32; ++kk) {
      const float4 wf = *(const float4*)&sWT[kk][tdl*4];
      const float2 df = *(const float2*)&sDT[kk][tbl*2];
      const float w[4] = {wf.x, wf.y, wf.z, wf.w};
#pragma unroll
      for (int a = 0; a < 4; ++a) {
        acc[a][0] = fmaf(w[a], df.x, acc[a][0]);
        acc[a][1] = fmaf(w[a], df.y, acc[a][1]);
      }
    }
  }

  const float4 b4 = *(const float4*)&bdt[d0 + tdl * 4];
  const float bv[4] = {b4.x, b4.y, b4.z, b4.w};
#pragma unroll
  for (int ib = 0; ib < 2; ++ib) {
    const int b = b0 + tbl * 2 + ib;
    float o[4];
#pragma unroll
    for (int a = 0; a < 4; ++a) {
      const float pre = acc[a][ib] + bv[a];
      o[a] = (pre > 20.f) ? pre : log1pf(__expf(pre));
    }
    *(float4*)&dt[(size_t)b * DIN + d0 + tdl * 4] = make_float4(o[0], o[1], o[2], o[3]);
  }
}

// ---------------------------------------------------------------------------
// Kernel 3: streaming state update + y, COALESCED h.
// A quad of lanes (q=0..3) owns one (b,d): lane q loads h[bd][4q..4q+4) so
// lane i's byte address = base + i*16 -> fully coalesced. Quad-reduce via
// __shfl_xor(1),(2); lane q==0 writes y. Block 256 = 64 bd; one b per block
// (64 | 5120). grid = 512*5120/64 = 40960 blocks.
// ---------------------------------------------------------------------------
__global__ __launch_bounds__(256) void k_y(
    const float* __restrict__ dt, const float* __restrict__ Bc,
    const float* __restrict__ Cc, const float* __restrict__ A,
    const float* __restrict__ Dp, const float* __restrict__ x,
    const float* __restrict__ h,  float* __restrict__ y)
{
  const int g = blockIdx.x * 64 + (threadIdx.x >> 2);  // (b,d) flat index
  const int q = threadIdx.x & 3;
  const int b = g / DIN;
  const int d = g - b * DIN;

  const float dtv = dt[g];
  const float xv  = x[g];
  const float dtx = dtv * xv;

  const float4 h4 = *(const float4*)(h  + (size_t)g * DST + q * 4);
  const float4 A4 = *(const float4*)(A  + (size_t)d * DST + q * 4);
  const float4 B4 = *(const float4*)(Bc + (size_t)b * DST + q * 4);
  const float4 C4 = *(const float4*)(Cc + (size_t)b * DST + q * 4);

  float p;
  {
    const float dA0 = __expf(A4.x * dtv);
    const float dA1 = __expf(A4.y * dtv);
    const float dA2 = __expf(A4.z * dtv);
    const float dA3 = __expf(A4.w * dtv);
    const float hn0 = fmaf(dA0, h4.x, dtx * B4.x);
    const float hn1 = fmaf(dA1, h4.y, dtx * B4.y);
    const float hn2 = fmaf(dA2, h4.z, dtx * B4.z);
    const float hn3 = fmaf(dA3, h4.w, dtx * B4.w);
    p = hn0 * C4.x + hn1 * C4.y + hn2 * C4.z + hn3 * C4.w;
  }
  p += __shfl_xor(p, 1);
  p += __shfl_xor(p, 2);
  if (q == 0) y[g] = fmaf(Dp[d], xv, p);
}

extern "C" void kernel_launch(void* const* d_in, const int* in_sizes, int n_in,
                              void* d_out, int out_size, void* d_ws, size_t ws_size,
                              hipStream_t stream) {
  const float* x    = (const float*)d_in[0];
  const float* Wdtr = (const float*)d_in[1];
  const float* Wdt  = (const float*)d_in[2];
  const float* bdt  = (const float*)d_in[3];
  const float* WB   = (const float*)d_in[4];
  const float* WC   = (const float*)d_in[5];
  const float* A    = (const float*)d_in[6];
  const float* Dp   = (const float*)d_in[7];
  const float* h    = (const float*)d_in[8];
  float* y = (float*)d_out;

  float* ws_part = (float*)d_ws;
  float* ws_dtr  = ws_part + (size_t)NZ * 3 * 8 * 4096;
  float* ws_B    = ws_dtr + (size_t)BATCH * RK;
  float* ws_C    = ws_B   + (size_t)BATCH * DST;
  float* ws_dt   = ws_C   + (size_t)BATCH * DST;

  k_proj<<<dim3(3, 8, NZ), 256, 0, stream>>>(x, Wdtr, WB, WC, ws_part);
  k_reduce<<<dim3(384), 256, 0, stream>>>(ws_part, ws_dtr, ws_B, ws_C);
  k_dt<<<dim3(80, 16), 256, 0, stream>>>(ws_dtr, Wdt, bdt, ws_dt);
  k_y<<<dim3((BATCH * DIN) / 64), 256, 0, stream>>>(ws_dt, ws_B, ws_C, A, Dp, x, h, y);
}